// Round 7
// baseline (11.008 us; speedup 1.0000x reference)
//
#include <hip/hip_runtime.h>

// Problem constants (match reference file)
#define S_SAMPLES 1000
#define DIM 512        // floats per row = 128 float4s
#define NBLOCKS 64     // 64 blocks x 16 waves = 1024 waves; 24 idle-guarded
#define NTHREADS 1024
#define WAVES_PER_BLOCK 16

// Single-node fused kernel, last-block-done reduction, agent-scope relaxed
// atomics only (no __threadfence / L2 writeback).
//  Phase 1: one 64-lane wave per sample (coalesced float4 row reads,
//           butterfly reduce, violation into LDS). Waves with s >= 1000
//           contribute 0.
//  Epilogue (wave 0 only): lanes 0..15 read the 16 wave-violations from LDS
//           in parallel and 4-stage-butterfly them (fixed tree order ->
//           deterministic). Lane 0 publishes with a relaxed agent
//           atomic_exchange; the swap's returned value is consumed (asm) so
//           the hardware ack orders it before the counter fetch_add. Last
//           arriving block ((c & 63) == 63 -- correct for ANY poisoned
//           initial counter value) gathers the 64 partials (one relaxed
//           agent atomic load per lane), butterflies, lane 0 writes mean.
//           Waves 1..15 retire right after the barrier -- no second barrier.
__global__ __launch_bounds__(NTHREADS) void trans_fused(
    const float* __restrict__ emb,
    const int* __restrict__ i_idx,
    const int* __restrict__ j_idx,
    const int* __restrict__ k_idx,
    unsigned int* __restrict__ part,    // NBLOCKS u32 (float bits) in d_ws
    unsigned int* __restrict__ counter, // 1 uint in d_ws (never initialized)
    float* __restrict__ out)
{
    __shared__ float vsh[WAVES_PER_BLOCK];

    const int wave = threadIdx.x >> 6;                    // 0..15
    const int lane = threadIdx.x & 63;
    const int s    = blockIdx.x * WAVES_PER_BLOCK + wave; // sample id

    // ---- Phase 1: per-sample violation ----
    if (s < S_SAMPLES) {
        const long long ri = (long long)i_idx[s] * DIM;
        const long long rj = (long long)j_idx[s] * DIM;
        const long long rk = (long long)k_idx[s] * DIM;
        const float4* pi = (const float4*)(emb + ri);
        const float4* pj = (const float4*)(emb + rj);
        const float4* pk = (const float4*)(emb + rk);

        float dij = 0.f, djk = 0.f, dik = 0.f;
        float nii = 0.f, njj = 0.f, nkk = 0.f;

#pragma unroll
        for (int t = 0; t < 2; ++t) {
            const int o = lane + 64 * t;   // 0..127 float4 index within row
            float4 a = pi[o];
            float4 b = pj[o];
            float4 c = pk[o];
            dij += a.x*b.x + a.y*b.y + a.z*b.z + a.w*b.w;
            djk += b.x*c.x + b.y*c.y + b.z*c.z + b.w*c.w;
            dik += a.x*c.x + a.y*c.y + a.z*c.z + a.w*c.w;
            nii += a.x*a.x + a.y*a.y + a.z*a.z + a.w*a.w;
            njj += b.x*b.x + b.y*b.y + b.z*b.z + b.w*b.w;
            nkk += c.x*c.x + c.y*c.y + c.z*c.z + c.w*c.w;
        }

#pragma unroll
        for (int off = 32; off > 0; off >>= 1) {
            dij += __shfl_xor(dij, off);
            djk += __shfl_xor(djk, off);
            dik += __shfl_xor(dik, off);
            nii += __shfl_xor(nii, off);
            njj += __shfl_xor(njj, off);
            nkk += __shfl_xor(nkk, off);
        }

        if (lane == 0) {
            const float EPS = 1e-12f;
            const float ni = fmaxf(sqrtf(nii), EPS);
            const float nj = fmaxf(sqrtf(njj), EPS);
            const float nk = fmaxf(sqrtf(nkk), EPS);
            const float sij = dij / (ni * nj);
            const float sjk = djk / (nj * nk);
            const float sik = dik / (ni * nk);
            // TEMPERATURE == 1.0
            const float pij = 1.f / (1.f + expf(-sij));
            const float pjk = 1.f / (1.f + expf(-sjk));
            const float pik = 1.f / (1.f + expf(-sik));
            vsh[wave] = fmaxf(pij * pjk - pik, 0.f);
        }
    } else {
        if (lane == 0) vsh[wave] = 0.f;
    }

    __syncthreads();

    // ---- Epilogue: wave 0 only ----
    if (threadIdx.x < 64) {
        // Parallel block-sum: lanes 0..15 read the 16 wave partials
        // (bank-conflict-free) and butterfly within the closed 16-lane
        // group (offsets 8,4,2,1 keep lanes 0..15 among themselves).
        float p = (lane < WAVES_PER_BLOCK) ? vsh[lane] : 0.f;
        p += __shfl_xor(p, 8);
        p += __shfl_xor(p, 4);
        p += __shfl_xor(p, 2);
        p += __shfl_xor(p, 1);

        int last = 0;
        if (lane == 0) {
            const unsigned int bits = __float_as_uint(p);
            const unsigned int old_bits = __hip_atomic_exchange(
                &part[blockIdx.x], bits, __ATOMIC_RELAXED,
                __HIP_MEMORY_SCOPE_AGENT);
            // Consume the ack: the swap's response must arrive before the
            // counter add issues -> partial visible before the count.
            asm volatile("" :: "v"(old_bits) : "memory");
            const unsigned int c = __hip_atomic_fetch_add(
                counter, 1u, __ATOMIC_RELAXED, __HIP_MEMORY_SCOPE_AGENT);
            last = ((c & (unsigned int)(NBLOCKS - 1)) ==
                    (unsigned int)(NBLOCKS - 1));
        }
        last = __shfl(last, 0);      // broadcast within wave 0

        if (last) {
            const unsigned int b = __hip_atomic_load(
                &part[lane], __ATOMIC_RELAXED, __HIP_MEMORY_SCOPE_AGENT);
            float acc = __uint_as_float(b);
#pragma unroll
            for (int off = 32; off > 0; off >>= 1) acc += __shfl_xor(acc, off);
            if (lane == 0) out[0] = acc * (1.0f / (float)S_SAMPLES);
        }
    }
}

extern "C" void kernel_launch(void* const* d_in, const int* in_sizes, int n_in,
                              void* d_out, int out_size, void* d_ws, size_t ws_size,
                              hipStream_t stream) {
    const float* emb  = (const float*)d_in[0];
    const int* i_idx  = (const int*)d_in[1];
    const int* j_idx  = (const int*)d_in[2];
    const int* k_idx  = (const int*)d_in[3];
    float* out  = (float*)d_out;

    unsigned int* part    = (unsigned int*)d_ws;                 // 64 u32
    unsigned int* counter = (unsigned int*)((char*)d_ws + 4096); // uninit OK

    trans_fused<<<NBLOCKS, NTHREADS, 0, stream>>>(emb, i_idx, j_idx, k_idx,
                                                  part, counter, out);
}

// Round 8
// 9.818 us; speedup vs baseline: 1.1213x; 1.1213x over previous
//
#include <hip/hip_runtime.h>

// Problem constants (match reference file)
#define S_SAMPLES 1000
#define DIM 512        // floats per row = 128 float4s
#define NBLOCKS 64     // 64 blocks x 16 waves = 1024 waves; 24 idle-guarded
#define NTHREADS 1024
#define WAVES_PER_BLOCK 16

// Single-node fused kernel, last-block-done reduction, agent-scope relaxed
// atomics only (no __threadfence / L2 writeback). Best-measured variant
// (R6, 9.74 us): serial thread-0 block-sum, no second barrier.
//  Phase 1: one 64-lane wave per sample (coalesced float4 row reads,
//           butterfly reduce, violation into LDS). Waves with s >= 1000
//           contribute 0.
//  Epilogue: thread 0 sums the block's 16 violations (fixed order),
//           publishes with relaxed agent atomic_exchange; the swap's return
//           value is consumed (asm) so the hardware ack orders it before the
//           counter fetch_add. Last arriving block ((c & 63) == 63 --
//           correct for ANY poisoned initial counter value) is detected by
//           thread 0, broadcast within wave 0 by __shfl; wave 0 alone loads
//           the 64 partials (one relaxed agent atomic load per lane),
//           butterfly-reduces in fixed order, lane 0 writes the mean.
//           Waves 1..15 retire right after the publish -- no second barrier.
__global__ __launch_bounds__(NTHREADS) void trans_fused(
    const float* __restrict__ emb,
    const int* __restrict__ i_idx,
    const int* __restrict__ j_idx,
    const int* __restrict__ k_idx,
    unsigned int* __restrict__ part,    // NBLOCKS u32 (float bits) in d_ws
    unsigned int* __restrict__ counter, // 1 uint in d_ws (never initialized)
    float* __restrict__ out)
{
    __shared__ float vsh[WAVES_PER_BLOCK];

    const int wave = threadIdx.x >> 6;                    // 0..15
    const int lane = threadIdx.x & 63;
    const int s    = blockIdx.x * WAVES_PER_BLOCK + wave; // sample id

    // ---- Phase 1: per-sample violation ----
    if (s < S_SAMPLES) {
        const long long ri = (long long)i_idx[s] * DIM;
        const long long rj = (long long)j_idx[s] * DIM;
        const long long rk = (long long)k_idx[s] * DIM;
        const float4* pi = (const float4*)(emb + ri);
        const float4* pj = (const float4*)(emb + rj);
        const float4* pk = (const float4*)(emb + rk);

        float dij = 0.f, djk = 0.f, dik = 0.f;
        float nii = 0.f, njj = 0.f, nkk = 0.f;

#pragma unroll
        for (int t = 0; t < 2; ++t) {
            const int o = lane + 64 * t;   // 0..127 float4 index within row
            float4 a = pi[o];
            float4 b = pj[o];
            float4 c = pk[o];
            dij += a.x*b.x + a.y*b.y + a.z*b.z + a.w*b.w;
            djk += b.x*c.x + b.y*c.y + b.z*c.z + b.w*c.w;
            dik += a.x*c.x + a.y*c.y + a.z*c.z + a.w*c.w;
            nii += a.x*a.x + a.y*a.y + a.z*a.z + a.w*a.w;
            njj += b.x*b.x + b.y*b.y + b.z*b.z + b.w*b.w;
            nkk += c.x*c.x + c.y*c.y + c.z*c.z + c.w*c.w;
        }

#pragma unroll
        for (int off = 32; off > 0; off >>= 1) {
            dij += __shfl_xor(dij, off);
            djk += __shfl_xor(djk, off);
            dik += __shfl_xor(dik, off);
            nii += __shfl_xor(nii, off);
            njj += __shfl_xor(njj, off);
            nkk += __shfl_xor(nkk, off);
        }

        if (lane == 0) {
            const float EPS = 1e-12f;
            const float ni = fmaxf(sqrtf(nii), EPS);
            const float nj = fmaxf(sqrtf(njj), EPS);
            const float nk = fmaxf(sqrtf(nkk), EPS);
            const float sij = dij / (ni * nj);
            const float sjk = djk / (nj * nk);
            const float sik = dik / (ni * nk);
            // TEMPERATURE == 1.0
            const float pij = 1.f / (1.f + expf(-sij));
            const float pjk = 1.f / (1.f + expf(-sjk));
            const float pik = 1.f / (1.f + expf(-sik));
            vsh[wave] = fmaxf(pij * pjk - pik, 0.f);
        }
    } else {
        if (lane == 0) vsh[wave] = 0.f;
    }

    __syncthreads();

    // ---- Epilogue: thread 0 publishes partial, bumps counter ----
    int last = 0;
    if (threadIdx.x == 0) {
        float p = 0.f;
#pragma unroll
        for (int w = 0; w < WAVES_PER_BLOCK; ++w) p += vsh[w]; // fixed order
        const unsigned int bits = __float_as_uint(p);
        const unsigned int old_bits = __hip_atomic_exchange(
            &part[blockIdx.x], bits, __ATOMIC_RELAXED, __HIP_MEMORY_SCOPE_AGENT);
        // Consume the ack: the swap's response must arrive before the
        // counter add issues -> partials are visible before counts.
        asm volatile("" :: "v"(old_bits) : "memory");
        const unsigned int c = __hip_atomic_fetch_add(
            counter, 1u, __ATOMIC_RELAXED, __HIP_MEMORY_SCOPE_AGENT);
        last = ((c & (unsigned int)(NBLOCKS - 1)) == (unsigned int)(NBLOCKS - 1));
    }

    // ---- Wave 0 of the last arriving block: final reduction ----
    if (threadIdx.x < 64) {
        last = __shfl(last, 0);      // broadcast thread 0's flag within wave 0
        if (last) {
            const unsigned int b = __hip_atomic_load(
                &part[lane], __ATOMIC_RELAXED, __HIP_MEMORY_SCOPE_AGENT);
            float acc = __uint_as_float(b);
#pragma unroll
            for (int off = 32; off > 0; off >>= 1) acc += __shfl_xor(acc, off);
            if (lane == 0) out[0] = acc * (1.0f / (float)S_SAMPLES);
        }
    }
}

extern "C" void kernel_launch(void* const* d_in, const int* in_sizes, int n_in,
                              void* d_out, int out_size, void* d_ws, size_t ws_size,
                              hipStream_t stream) {
    const float* emb  = (const float*)d_in[0];
    const int* i_idx  = (const int*)d_in[1];
    const int* j_idx  = (const int*)d_in[2];
    const int* k_idx  = (const int*)d_in[3];
    float* out  = (float*)d_out;

    unsigned int* part    = (unsigned int*)d_ws;                 // 64 u32
    unsigned int* counter = (unsigned int*)((char*)d_ws + 4096); // uninit OK

    trans_fused<<<NBLOCKS, NTHREADS, 0, stream>>>(emb, i_idx, j_idx, k_idx,
                                                  part, counter, out);
}